// Round 5
// baseline (126.284 us; speedup 1.0000x reference)
//
#include <hip/hip_runtime.h>
#include <math.h>

#define NH 192
#define NW 192
#define Wt 193
#define TG 24              // xt tiles per dim (192/8)
#define NTILE (TG*TG)      // 576 (xt tiles / k_prep tile blocks)
#define NMAIN 1152         // k_main blocks: 48 k1-groups x 24 k2-groups
#define TILE_SZ 4096       // 64 j * 64 p
#define TBLK 3072          // table-builder blocks in fused prep kernel

// cos(2*pi*num/den) via HW cos (input in revolutions)
__device__ __forceinline__ float cos_rev(float num, float den) {
    float rev = num * __builtin_amdgcn_rcpf(den);
    rev = __builtin_amdgcn_fractf(rev);
    return __builtin_amdgcn_cosf(rev);
}

// ---------------- fused prep: tables + x ----------------
// EXACT round-0 version (passed twice). blocks [0,TBLK): build both tables:
//   Cz [j][kg][i][r] = cos(2*pi*(kg*4+r)/(i*64+j+2))          (k2 side, float4-packed)
//   CP1[j][k][i]     = cos(2*pi*k/(i*64+j+2)) * P[i][j]       (k1 side, row-packed)
// blocks [TBLK, TBLK+576): xt[tile][j][p] = (win_avg @ M^T), p = l1*8+l2 local
__global__ __launch_bounds__(256) void k_prep(const float* __restrict__ grid,
                                              const float* __restrict__ Mw,
                                              const float* __restrict__ P,
                                              float* __restrict__ Cz,
                                              float* __restrict__ CP1,
                                              float* __restrict__ xt) {
    __shared__ float Ms[64 * 64];    // M[j][c]
    __shared__ float win[64 * 68];   // win[p][c], stride 68
    int bx = blockIdx.x;
    int t = threadIdx.x;

    if (bx < TBLK) {
        int idx = bx * 256 + t;                 // 0..786431
        // Cz entry
        int r  = idx & 3;
        int i  = (idx >> 2) & 63;
        int kg = (idx >> 8) % 48;
        int j  = idx / 12288;
        int k  = kg * 4 + r;
        Cz[idx] = cos_rev((float)k, (float)(i * 64 + j + 2));
        // CP1 entry (different mapping, same flat size): [j][k][i] layout
        int i2 = idx & 63;
        int k2 = (idx >> 6) % 192;
        int j2 = idx / 12288;
        int t2 = i2 * 64 + j2;
        CP1[idx] = cos_rev((float)k2, (float)(t2 + 2)) * P[t2];
        return;
    }

    int bb = bx - TBLK;                         // 0..575
    int k1g = bb % TG, k2g = bb / TG;

    // stage M (coalesced)
    #pragma unroll
    for (int r = 0; r < 4; ++r) {
        int e = r * 256 + t;
        ((float4*)Ms)[e] = ((const float4*)Mw)[e];
    }

    // window averages: lane = channel c
    {
        int c = t & 63, pq = t >> 6;
        const float* gb = grid + ((size_t)(k1g * 8) * Wt + k2g * 8) * 64;
        #pragma unroll
        for (int r = 0; r < 16; ++r) {
            int p = pq * 16 + r;
            int l1 = p >> 3, l2 = p & 7;
            const float* g0 = gb + ((size_t)l1 * Wt + l2) * 64;
            float s = g0[c] + g0[64 + c] + g0[Wt * 64 + c] + g0[Wt * 64 + 64 + c];
            win[p * 68 + c] = 0.25f * s;
        }
    }
    __syncthreads();

    // x[p][j] = sum_c win[p][c] * M[j][c]; lane = p -> coalesced stores
    int p = t & 63, jq = t >> 6;
    float4 wv[16];
    #pragma unroll
    for (int q = 0; q < 16; ++q) wv[q] = *(const float4*)&win[p * 68 + 4 * q];

    float* xb = xt + (size_t)(k1g * TG + k2g) * TILE_SZ;
    #pragma unroll
    for (int r = 0; r < 16; ++r) {
        int j = jq * 16 + r;
        float acc = 0.f;
        #pragma unroll
        for (int q = 0; q < 16; ++q) {
            float4 mv = *(const float4*)&Ms[j * 64 + 4 * q];   // uniform broadcast
            acc += wv[q].x * mv.x + wv[q].y * mv.y + wv[q].z * mv.z + wv[q].w * mv.w;
        }
        xb[(size_t)j * 64 + p] = acc;    // coalesced
    }
}

// ---------------- k_main v5: Nk[b,i] ----------------
// v1's proven inner loop (per jj per thread: 1 coalesced c1 dword + 2
// ds_read_b128 (c2) + 2 uniform x float4 + 16 VALU), new schedule:
//  - 1152 blocks x 256 thr (4 waves): block = 4 k1-rows x 8 k2-cols.
//    Wave w owns k1-row; thread tile 1x8 (identical to v1). Load imbalance
//    33% -> 11%; ~4.5 blocks/CU resident (32KB LDS).
//  - double-buffered c2 staging, ONE barrier per 8-jj chunk: issue next
//    chunk's 4 float4 loads -> regs BEFORE compute, ds_write after compute.
//    Staging L2 latency hides under compute instead of draining at barrier.
//    Safety: a wave ds_writing buf B passed the previous barrier, which all
//    waves pass only after finishing their reads of B's old contents.
__global__ __launch_bounds__(256) void k_main(const float* __restrict__ xt,
                                              const float* __restrict__ Cz,
                                              const float* __restrict__ CP1,
                                              float* __restrict__ out) {
    __shared__ float4 cs[2048];      // 2 bufs x 16KB: [buf][jj(8)][g(2)][i(64)]
    int bx = blockIdx.x;             // k1-group fastest: 48 consecutive blocks
    int k1G = bx % 48, k2g = bx / 48;    // share the same c2 slice (L2-hot)
    int t = threadIdx.x;
    int lane = t & 63;               // i
    int w = __builtin_amdgcn_readfirstlane(t >> 6);   // 0..3 = local k1 row
    int k1 = k1G * 4 + w;

    const float* c1p = CP1 + (size_t)k1 * 64 + lane;                 // +12288/j
    // xt tile is 8x8: tile = (k1G>>1)*TG + k2g; within-tile row wl
    int wl = (k1G & 1) * 4 + w;
    const float* xb = xt + (size_t)((k1G >> 1) * TG + k2g) * TILE_SZ + wl * 8;
    const float4* Cz4 = (const float4*)Cz;
    int kgb = k2g * 2;

    float acc[8];
    #pragma unroll
    for (int l2 = 0; l2 < 8; ++l2) acc[l2] = 0.f;

    float4 stg[4];
    // prologue: stage chunk 0 into buf 0
    #pragma unroll
    for (int r = 0; r < 4; ++r) {
        int e = r * 256 + t;         // [0,1024): jj = e>>7, g = (e>>6)&1, i = e&63
        stg[r] = Cz4[(size_t)(((e >> 7)) * 48 + kgb + ((e >> 6) & 1)) * 64 + (e & 63)];
    }
    #pragma unroll
    for (int r = 0; r < 4; ++r) cs[r * 256 + t] = stg[r];
    __syncthreads();

    for (int jc = 0; jc < 8; ++jc) {
        int cur = jc & 1;
        // issue next chunk's loads early (latency hides under compute below)
        if (jc < 7) {
            #pragma unroll
            for (int r = 0; r < 4; ++r) {
                int e = r * 256 + t;
                stg[r] = Cz4[(size_t)(((jc + 1) * 8 + (e >> 7)) * 48 + kgb
                                      + ((e >> 6) & 1)) * 64 + (e & 63)];
            }
        }

        #pragma unroll 4
        for (int jj = 0; jj < 8; ++jj) {
            int j = jc * 8 + jj;
            float  c1 = c1p[(size_t)j * 12288];              // coalesced dword (L2)
            float4 v0 = cs[cur * 1024 + jj * 128 + lane];    // ds_read_b128, cf
            float4 v1 = cs[cur * 1024 + jj * 128 + 64 + lane];
            const float4* xj = (const float4*)(xb + (size_t)j * 64);  // uniform
            float4 x0 = xj[0];
            float4 x1 = xj[1];
            float c2f[8] = {v0.x, v0.y, v0.z, v0.w, v1.x, v1.y, v1.z, v1.w};
            float xs[8]  = {x0.x, x0.y, x0.z, x0.w, x1.x, x1.y, x1.z, x1.w};
            #pragma unroll
            for (int l2 = 0; l2 < 8; ++l2)
                acc[l2] += xs[l2] * (c1 * c2f[l2]);
        }

        if (jc < 7) {                // write next buf (old contents consumed:
            #pragma unroll           // all waves passed the previous barrier)
            for (int r = 0; r < 4; ++r)
                cs[(cur ^ 1) * 1024 + r * 256 + t] = stg[r];
        }
        __syncthreads();
    }

    size_t ob = ((size_t)k1 * NW + k2g * 8) * 64 + lane;
    #pragma unroll
    for (int l2 = 0; l2 < 8; ++l2)
        out[ob + (size_t)l2 * 64] = acc[l2];  // coalesced dword stores
}

extern "C" void kernel_launch(void* const* d_in, const int* in_sizes, int n_in,
                              void* d_out, int out_size, void* d_ws, size_t ws_size,
                              hipStream_t stream) {
    const float* grid = (const float*)d_in[0];   // [193,193,64]
    const float* Mw   = (const float*)d_in[1];   // [64,64]
    const float* P    = (const float*)d_in[2];   // [64,64]
    float* out = (float*)d_out;                  // [36864,64]

    // ws layout (floats): Cz [786432] | CP1 [786432] | xt [576*4096]
    float* Cz  = (float*)d_ws;
    float* CP1 = Cz + 786432;
    float* xt  = CP1 + 786432;

    k_prep<<<TBLK + NTILE, 256, 0, stream>>>(grid, Mw, P, Cz, CP1, xt);
    k_main<<<NMAIN, 256, 0, stream>>>(xt, Cz, CP1, out);
}

// Round 6
// 95.411 us; speedup vs baseline: 1.3236x; 1.3236x over previous
//
#include <hip/hip_runtime.h>
#include <math.h>

#define NH 192
#define NW 192
#define Wt 193
#define TG 24              // xt tiles per dim (192/8)
#define NTILE (TG*TG)      // 576 xt-tile blocks
#define TILE_SZ 4096       // 64 j * 64 p
#define NMAIN 768          // k_main blocks: 192 k1 x 4 k2-chunks
#define CHUNK 48

// cos(2*pi*num*rcpden) via HW cos (input in revolutions)
__device__ __forceinline__ float cos_revr(float num, float rcpden) {
    float rev = num * rcpden;
    rev = __builtin_amdgcn_fractf(rev);
    return __builtin_amdgcn_cosf(rev);
}

// ---------------- k_prep-lite: xt only (proven tile code, table branch deleted) ----
// block bb in [0,576): xt[tile][j][p] = (win_avg @ M^T), p = l1*8+l2 local
__global__ __launch_bounds__(256) void k_prep(const float* __restrict__ grid,
                                              const float* __restrict__ Mw,
                                              float* __restrict__ xt) {
    __shared__ float Ms[64 * 64];    // M[j][c]
    __shared__ float win[64 * 68];   // win[p][c], stride 68
    int bb = blockIdx.x;             // 0..575
    int t = threadIdx.x;
    int k1g = bb % TG, k2g = bb / TG;

    // stage M (coalesced)
    #pragma unroll
    for (int r = 0; r < 4; ++r) {
        int e = r * 256 + t;
        ((float4*)Ms)[e] = ((const float4*)Mw)[e];
    }

    // window averages: lane = channel c
    {
        int c = t & 63, pq = t >> 6;
        const float* gb = grid + ((size_t)(k1g * 8) * Wt + k2g * 8) * 64;
        #pragma unroll
        for (int r = 0; r < 16; ++r) {
            int p = pq * 16 + r;
            int l1 = p >> 3, l2 = p & 7;
            const float* g0 = gb + ((size_t)l1 * Wt + l2) * 64;
            float s = g0[c] + g0[64 + c] + g0[Wt * 64 + c] + g0[Wt * 64 + 64 + c];
            win[p * 68 + c] = 0.25f * s;
        }
    }
    __syncthreads();

    // x[p][j] = sum_c win[p][c] * M[j][c]; lane = p -> coalesced stores
    int p = t & 63, jq = t >> 6;
    float4 wv[16];
    #pragma unroll
    for (int q = 0; q < 16; ++q) wv[q] = *(const float4*)&win[p * 68 + 4 * q];

    float* xb = xt + (size_t)(k1g * TG + k2g) * TILE_SZ;
    #pragma unroll
    for (int r = 0; r < 16; ++r) {
        int j = jq * 16 + r;
        float acc = 0.f;
        #pragma unroll
        for (int q = 0; q < 16; ++q) {
            float4 mv = *(const float4*)&Ms[j * 64 + 4 * q];   // uniform broadcast
            acc += wv[q].x * mv.x + wv[q].y * mv.y + wv[q].z * mv.z + wv[q].w * mv.w;
        }
        xb[(size_t)j * 64 + p] = acc;    // coalesced
    }
}

// ---------------- k_main v6: table-free via Chebyshev recurrence ----------------
// 768 blocks (192 k1 x 4 chunks of 48 k2) x 256 thr (4 waves) = exactly
// 3 blocks/CU, zero tail. Thread = (i=lane, wave w owns j in [16w,16w+16)).
// c2[k2] = cos(2*pi*k2/T), T = 64i+j+2, via c_{k+1} = A*c_k - c_{k-1},
// A = 2cos(2*pi/T) in regs; re-seeded every 16 k2 (drift < ~3e-4).
// c1v[j] = cos(2*pi*k1/T)*P[i][j] in regs. x staged once to LDS (12 KB).
// Inner loop: 4 uniform ds_read_b128 (x) + 48 VALU + 1 b32 part-write.
// No table reads at all -> the HBM-latency bottleneck v5 exposed is gone.
__global__ __launch_bounds__(256, 3) void k_main(const float* __restrict__ xt,
                                                 const float* __restrict__ P,
                                                 float* __restrict__ out) {
    __shared__ float xls[CHUNK * 68];   // x[k2l][j], stride 68 (13 KB)
    __shared__ float pp[4096];          // P^T[j][i] (init) then part[w][16][64]
    int bx = blockIdx.x;
    int k1 = bx >> 2;
    int c  = bx & 3;
    int k2s = c * CHUNK;
    int t = threadIdx.x;
    int lane = t & 63;                  // i
    int w = __builtin_amdgcn_readfirstlane(t >> 6);   // 0..3
    int jb = w * 16;

    // ---- stage P transposed: pp[j*64+i] = P[i*64+j] (coalesced reads) ----
    {
        const float4* P4 = (const float4*)P;
        #pragma unroll
        for (int s = 0; s < 4; ++s) {
            int e = s * 256 + t;        // i = e>>4, j0 = (e&15)*4
            float4 v = P4[e];
            int i = e >> 4, j0 = (e & 15) * 4;
            pp[(j0 + 0) * 64 + i] = v.x;
            pp[(j0 + 1) * 64 + i] = v.y;
            pp[(j0 + 2) * 64 + i] = v.z;
            pp[(j0 + 3) * 64 + i] = v.w;
        }
    }
    // ---- stage x: xls[k2l*68+j] from xt[tile][j][p]; each word read once globally ----
    {
        int prow = k1 & 7;
        const float4* xt4 = (const float4*)xt
                          + (size_t)((k1 >> 3) * TG + c * 6) * (TILE_SZ / 4);
        #pragma unroll
        for (int s = 0; s < 3; ++s) {
            int f = s * 256 + t;        // [0,768): j = f/12, u = f%12
            int j = f / 12, u = f - 12 * j;
            int tc = u >> 1, h = u & 1; // tile-col 0..5, half 0..1
            float4 v = xt4[tc * 1024 + j * 16 + prow * 2 + h];
            int k2l = tc * 8 + h * 4;
            xls[(k2l + 0) * 68 + j] = v.x;
            xls[(k2l + 1) * 68 + j] = v.y;
            xls[(k2l + 2) * 68 + j] = v.z;
            xls[(k2l + 3) * 68 + j] = v.w;
        }
    }
    __syncthreads();

    // ---- per-thread init: A and c1v in registers (16 j each) ----
    float A[16], c1v[16], ce[16], co[16];
    #pragma unroll
    for (int jl = 0; jl < 16; ++jl) {
        float T  = (float)(lane * 64 + jb + jl + 2);
        float rT = __builtin_amdgcn_rcpf(T);
        A[jl]   = 2.0f * cos_revr(1.0f, rT);
        c1v[jl] = cos_revr((float)k1, rT) * pp[(jb + jl) * 64 + lane];
    }
    __syncthreads();                    // all waves done reading pp -> reuse as part

    float* part = pp;                   // [w][k2l 16][i 64]
    for (int sub = 0; sub < 3; ++sub) {
        int k2a = k2s + sub * 16;
        // re-seed recurrence (caps drift; 16 rcp + 32 cos per thread)
        #pragma unroll
        for (int jl = 0; jl < 16; ++jl) {
            float T  = (float)(lane * 64 + jb + jl + 2);
            float rT = __builtin_amdgcn_rcpf(T);
            ce[jl] = cos_revr((float)k2a, rT);        // cos(k2a * theta)
            co[jl] = cos_revr((float)(k2a - 1), rT);  // cos((k2a-1) * theta)
        }
        #pragma unroll
        for (int nn = 0; nn < 8; ++nn) {
            {   // even step: current = ce, advance co
                const float4* xq = (const float4*)&xls[(sub * 16 + 2 * nn) * 68 + jb];
                float4 q0 = xq[0], q1 = xq[1], q2 = xq[2], q3 = xq[3];
                float xs[16] = {q0.x, q0.y, q0.z, q0.w, q1.x, q1.y, q1.z, q1.w,
                                q2.x, q2.y, q2.z, q2.w, q3.x, q3.y, q3.z, q3.w};
                float psum = 0.f;
                #pragma unroll
                for (int jl = 0; jl < 16; ++jl) {
                    psum   = fmaf(xs[jl] * c1v[jl], ce[jl], psum);
                    co[jl] = fmaf(A[jl], ce[jl], -co[jl]);
                }
                part[(w * 16 + 2 * nn) * 64 + lane] = psum;
            }
            {   // odd step: current = co, advance ce
                const float4* xq = (const float4*)&xls[(sub * 16 + 2 * nn + 1) * 68 + jb];
                float4 q0 = xq[0], q1 = xq[1], q2 = xq[2], q3 = xq[3];
                float xs[16] = {q0.x, q0.y, q0.z, q0.w, q1.x, q1.y, q1.z, q1.w,
                                q2.x, q2.y, q2.z, q2.w, q3.x, q3.y, q3.z, q3.w};
                float psum = 0.f;
                #pragma unroll
                for (int jl = 0; jl < 16; ++jl) {
                    psum   = fmaf(xs[jl] * c1v[jl], co[jl], psum);
                    ce[jl] = fmaf(A[jl], co[jl], -ce[jl]);
                }
                part[(w * 16 + 2 * nn + 1) * 64 + lane] = psum;
            }
        }
        __syncthreads();                // partials visible
        // reduce 4 wave-partials -> out (coalesced)
        #pragma unroll
        for (int s = 0; s < 4; ++s) {
            int e = s * 256 + t;        // k2l = e>>6, i = e&63
            float r = part[e] + part[1024 + e] + part[2048 + e] + part[3072 + e];
            out[((size_t)k1 * NW + (k2a + (e >> 6))) * 64 + (e & 63)] = r;
        }
        __syncthreads();                // part reusable next sub
    }
}

extern "C" void kernel_launch(void* const* d_in, const int* in_sizes, int n_in,
                              void* d_out, int out_size, void* d_ws, size_t ws_size,
                              hipStream_t stream) {
    const float* grid = (const float*)d_in[0];   // [193,193,64]
    const float* Mw   = (const float*)d_in[1];   // [64,64]
    const float* P    = (const float*)d_in[2];   // [64,64]
    float* out = (float*)d_out;                  // [36864,64]

    float* xt = (float*)d_ws;                    // [576*4096] floats

    k_prep<<<NTILE, 256, 0, stream>>>(grid, Mw, xt);
    k_main<<<NMAIN, 256, 0, stream>>>(xt, P, out);
}

// Round 7
// 95.326 us; speedup vs baseline: 1.3248x; 1.0009x over previous
//
#include <hip/hip_runtime.h>
#include <math.h>

#define NW 192
#define Wt 193
#define NMAIN 768          // 192 k1 x 4 k2-chunks; 256 CUs x 3 blocks, zero tail
#define CHUNK 48

// cos(2*pi*num*rcpden) via HW cos (input in revolutions)
__device__ __forceinline__ float cos_revr(float num, float rcpden) {
    float rev = num * rcpden;
    rev = __builtin_amdgcn_fractf(rev);
    return __builtin_amdgcn_cosf(rev);
}

// ---------------- k_fused v7: grid -> win -> x -> einsum -> out, one kernel ----
// Block b: k1 = b>>2, chunk c = b&3 (k2 in [48c, 48c+48)). 256 thr = 4 waves.
// Phase A: stage M -> bufB; win[48][64] -> bufA (lane = channel, coalesced).
// Phase B: x[p][j] = sum_c win[p][c]*M[j][c] -> xls[p*68+j] (lane = p, 48 active).
// Phase C: stage P^T -> bufA (win dead).
// Phase D: v6's proven Chebyshev einsum (part aliased onto bufB; Ms dead).
// No workspace, no intermediate HBM round-trip, one launch.
__global__ __launch_bounds__(256, 3) void k_fused(const float* __restrict__ grid,
                                                  const float* __restrict__ Mw,
                                                  const float* __restrict__ P,
                                                  float* __restrict__ out) {
    __shared__ float bufA[4096];        // win[48][68] (3264) -> P^T[j][i] (4096)
    __shared__ float bufB[4096];        // Ms[j][c] (4096)    -> part[4][16][64]
    __shared__ float xls[CHUNK * 68];   // x[k2l][j], stride 68 (13 KB)

    int bx = blockIdx.x;
    int k1  = bx >> 2;
    int k2s = (bx & 3) * CHUNK;
    int t = threadIdx.x;
    int lane = t & 63;                  // i (einsum) / c (win) / p (GEMM)
    int w = __builtin_amdgcn_readfirstlane(t >> 6);   // 0..3
    int jb = w * 16;

    // ---- Phase A: stage M (coalesced float4) + window averages ----
    #pragma unroll
    for (int r = 0; r < 4; ++r) {
        int e = r * 256 + t;
        ((float4*)bufB)[e] = ((const float4*)Mw)[e];
    }
    {
        int c = t & 63;
        const float* gb  = grid + ((size_t)k1 * Wt + k2s) * 64 + c;
        const float* gb1 = gb + (size_t)Wt * 64;
        #pragma unroll
        for (int r = 0; r < 12; ++r) {
            int p = w * 12 + r;         // 4 waves x 12 = 48 positions
            float s = gb[p * 64] + gb[(p + 1) * 64]
                    + gb1[p * 64] + gb1[(p + 1) * 64];
            bufA[p * 68 + c] = 0.25f * s;   // coalesced, conflict-light
        }
    }
    __syncthreads();                    // sync1: M + win visible

    // ---- Phase B: GEMM x[p][j] into xls (lane = p, wave w -> 16 j) ----
    if (lane < 48) {
        int p = lane;
        float4 wv[16];
        #pragma unroll
        for (int q = 0; q < 16; ++q) wv[q] = *(const float4*)&bufA[p * 68 + 4 * q];
        #pragma unroll
        for (int r = 0; r < 16; ++r) {
            int j = jb + r;
            const float4* mrow = (const float4*)&bufB[j * 64];  // uniform broadcast
            float acc = 0.f;
            #pragma unroll
            for (int q = 0; q < 16; ++q) {
                float4 mv = mrow[q];
                acc += wv[q].x * mv.x + wv[q].y * mv.y
                     + wv[q].z * mv.z + wv[q].w * mv.w;
            }
            xls[p * 68 + j] = acc;
        }
    }
    __syncthreads();                    // sync2: xls done; win + Ms now dead

    // ---- Phase C: stage P transposed into bufA: pp[j*64+i] = P[i*64+j] ----
    {
        const float4* P4 = (const float4*)P;
        #pragma unroll
        for (int s = 0; s < 4; ++s) {
            int e = s * 256 + t;        // i = e>>4, j0 = (e&15)*4
            float4 v = P4[e];
            int i = e >> 4, j0 = (e & 15) * 4;
            bufA[(j0 + 0) * 64 + i] = v.x;
            bufA[(j0 + 1) * 64 + i] = v.y;
            bufA[(j0 + 2) * 64 + i] = v.z;
            bufA[(j0 + 3) * 64 + i] = v.w;
        }
    }
    __syncthreads();                    // sync3: P^T visible

    // ---- Phase D: einsum via Chebyshev recurrence (v6's proven code) ----
    // Thread = (i = lane, wave w owns j in [16w, 16w+16)).
    // c2[k2] = cos(2*pi*k2/T), T = 64i+j+2: c_{k+1} = A*c_k - c_{k-1},
    // A = 2cos(2*pi/T); re-seeded every 16 k2 (drift < ~3e-4).
    float A[16], c1v[16], ce[16], co[16];
    #pragma unroll
    for (int jl = 0; jl < 16; ++jl) {
        float T  = (float)(lane * 64 + jb + jl + 2);
        float rT = __builtin_amdgcn_rcpf(T);
        A[jl]   = 2.0f * cos_revr(1.0f, rT);
        c1v[jl] = cos_revr((float)k1, rT) * bufA[(jb + jl) * 64 + lane];
    }

    float* part = bufB;                 // [w][k2l 16][i 64]; Ms dead since sync2
    for (int sub = 0; sub < 3; ++sub) {
        int k2a = k2s + sub * 16;
        // re-seed recurrence
        #pragma unroll
        for (int jl = 0; jl < 16; ++jl) {
            float T  = (float)(lane * 64 + jb + jl + 2);
            float rT = __builtin_amdgcn_rcpf(T);
            ce[jl] = cos_revr((float)k2a, rT);        // cos(k2a * theta)
            co[jl] = cos_revr((float)(k2a - 1), rT);  // cos((k2a-1) * theta)
        }
        #pragma unroll
        for (int nn = 0; nn < 8; ++nn) {
            {   // even step: current = ce, advance co
                const float4* xq = (const float4*)&xls[(sub * 16 + 2 * nn) * 68 + jb];
                float4 q0 = xq[0], q1 = xq[1], q2 = xq[2], q3 = xq[3];
                float xs[16] = {q0.x, q0.y, q0.z, q0.w, q1.x, q1.y, q1.z, q1.w,
                                q2.x, q2.y, q2.z, q2.w, q3.x, q3.y, q3.z, q3.w};
                float psum = 0.f;
                #pragma unroll
                for (int jl = 0; jl < 16; ++jl) {
                    psum   = fmaf(xs[jl] * c1v[jl], ce[jl], psum);
                    co[jl] = fmaf(A[jl], ce[jl], -co[jl]);
                }
                part[(w * 16 + 2 * nn) * 64 + lane] = psum;
            }
            {   // odd step: current = co, advance ce
                const float4* xq = (const float4*)&xls[(sub * 16 + 2 * nn + 1) * 68 + jb];
                float4 q0 = xq[0], q1 = xq[1], q2 = xq[2], q3 = xq[3];
                float xs[16] = {q0.x, q0.y, q0.z, q0.w, q1.x, q1.y, q1.z, q1.w,
                                q2.x, q2.y, q2.z, q2.w, q3.x, q3.y, q3.z, q3.w};
                float psum = 0.f;
                #pragma unroll
                for (int jl = 0; jl < 16; ++jl) {
                    psum   = fmaf(xs[jl] * c1v[jl], co[jl], psum);
                    ce[jl] = fmaf(A[jl], co[jl], -ce[jl]);
                }
                part[(w * 16 + 2 * nn + 1) * 64 + lane] = psum;
            }
        }
        __syncthreads();                // partials visible
        // reduce 4 wave-partials -> out (coalesced)
        #pragma unroll
        for (int s = 0; s < 4; ++s) {
            int e = s * 256 + t;        // k2l = e>>6, i = e&63
            float r = part[e] + part[1024 + e] + part[2048 + e] + part[3072 + e];
            out[((size_t)k1 * NW + (k2a + (e >> 6))) * 64 + (e & 63)] = r;
        }
        __syncthreads();                // part reusable next sub
    }
}

extern "C" void kernel_launch(void* const* d_in, const int* in_sizes, int n_in,
                              void* d_out, int out_size, void* d_ws, size_t ws_size,
                              hipStream_t stream) {
    const float* grid = (const float*)d_in[0];   // [193,193,64]
    const float* Mw   = (const float*)d_in[1];   // [64,64]
    const float* P    = (const float*)d_in[2];   // [64,64]
    float* out = (float*)d_out;                  // [36864,64]
    (void)d_ws; (void)ws_size;                   // workspace unused

    k_fused<<<NMAIN, 256, 0, stream>>>(grid, Mw, P, out);
}